// Round 6
// baseline (429.798 us; speedup 1.0000x reference)
//
#include <hip/hip_runtime.h>

#define NN 50000
#define EE 600000
#define DD 128
#define GG 256
#define LL 5
#define OO 10
#define BN_EPS 1e-5f
#define CPAD 515      // 512 combos + 3 sentinel (-1e30) rows (slot 0x02020202 -> cidx 514)
#define ESTRIDE 40    // fixed CSR slots per node (P(deg>40)~1e-9 at lambda=12)

// prep kernel block-range sizes (virtual ids; physical blocks are striped through
// all sections via a bijective mod-permutation so latency-bound atomic work
// overlaps BW-bound streaming work instead of running as serial phases)
#define B_SCAT  2344                       // ceil(EE/256)
#define B_COMBO 1288                       // ceil(LL*CPAD*DD / 256)
#define B_WT    160                        // 10 mats x 16 (32x32) tiles
#define B_CVT   3125                       // NN*DD/8 / 256 (pure convert)
#define B_POOL  2048                       // 8 blocks per graph
#define B_PREP  (B_SCAT + B_COMBO + B_WT + B_CVT + B_POOL)  // 8965 = 5*11*163, coprime w/ 1021

typedef __attribute__((ext_vector_type(8))) short short8;
typedef __attribute__((ext_vector_type(16))) float float16;

__device__ __forceinline__ unsigned short f2b(float f) {   // fp32 -> bf16 RNE
    unsigned u = __float_as_uint(f);
    unsigned r = u + 0x7FFFu + ((u >> 16) & 1u);
    return (unsigned short)(r >> 16);
}
__device__ __forceinline__ unsigned pk2(float lo, float hi) {
    return (unsigned)f2b(lo) | ((unsigned)f2b(hi) << 16);
}
__device__ __forceinline__ float blo(unsigned u) { return __uint_as_float(u << 16); }
__device__ __forceinline__ float bhi(unsigned u) { return __uint_as_float(u & 0xFFFF0000u); }

__device__ __forceinline__ void acc8(float* acc, uint4 xv, uint4 cv) {
    acc[0] += fmaxf(blo(xv.x) + blo(cv.x), 0.f);
    acc[1] += fmaxf(bhi(xv.x) + bhi(cv.x), 0.f);
    acc[2] += fmaxf(blo(xv.y) + blo(cv.y), 0.f);
    acc[3] += fmaxf(bhi(xv.y) + bhi(cv.y), 0.f);
    acc[4] += fmaxf(blo(xv.z) + blo(cv.z), 0.f);
    acc[5] += fmaxf(bhi(xv.z) + bhi(cv.z), 0.f);
    acc[6] += fmaxf(blo(xv.w) + blo(cv.w), 0.f);
    acc[7] += fmaxf(bhi(xv.w) + bhi(cv.w), 0.f);
}

// == mega prep: edge-scatter | combo | Wt-transpose | cvt_x | pool0 (striped) ==
__launch_bounds__(256)
__global__ void prep(const float* __restrict__ x, const int* __restrict__ ei,
                     const int* __restrict__ eattr, const int* __restrict__ batch,
                     const float* __restrict__ bond,
                     const float* __restrict__ w1, const float* __restrict__ w2,
                     unsigned* __restrict__ xb4, unsigned short* __restrict__ combo,
                     short* __restrict__ wt, int* __restrict__ epos,
                     unsigned* __restrict__ e_info, float* __restrict__ pooled0) {
    // bijective stripe: gcd(1021, 8965)=1 -> all sections co-resident
    const int bid = (int)(((long long)blockIdx.x * 1021) % B_PREP);
    const int t = threadIdx.x;
    if (bid < B_SCAT) {
        // scatter edges into fixed-stride CSR. Deps: epos==0, e_info==0x02020202
        // (both memset before launch). Unfilled slots stay = sentinel.
        int e = bid * 256 + t;
        if (e < EE) {
            int dst = ei[EE + e];
            int slot = atomicAdd(&epos[dst], 1);
            if (slot < ESTRIDE) {
                unsigned cidx = (unsigned)eattr[e * 3 + 0] | ((unsigned)eattr[e * 3 + 1] << 3)
                              | ((unsigned)eattr[e * 3 + 2] << 6);
                e_info[dst * ESTRIDE + slot] = (unsigned)ei[e] | (cidx << 16);
            }
        }
    } else if (bid < B_SCAT + B_COMBO) {
        int e = (bid - B_SCAT) * 256 + t;
        if (e < LL * CPAD * DD) {
            int l = e / (CPAD * DD), rem = e - l * (CPAD * DD);
            int c = rem / DD, d = rem - c * DD;
            float s;
            if (c >= 512) s = -1e30f;                     // sentinel rows: relu(x+s)==0
            else {
                const float* b_ = bond + (size_t)l * 3 * 8 * DD;
                s = b_[(c & 7) * DD + d] + b_[(8 + ((c >> 3) & 7)) * DD + d]
                  + b_[(16 + (c >> 6)) * DD + d];
            }
            combo[e] = f2b(s);
        }
    } else if (bid < B_SCAT + B_COMBO + B_WT) {
        // coalesced transpose: wt[mat][c][k] = bf16(W[mat][k][c]), 32x32 LDS tiles
        __shared__ float tile[32][33];
        int b = bid - B_SCAT - B_COMBO;
        int mat = b >> 4, tl = b & 15;
        int k0 = (tl >> 2) * 32, c0 = (tl & 3) * 32;
        const float* W = (mat < 5) ? (w1 + (size_t)mat * DD * DD)
                                   : (w2 + (size_t)(mat - 5) * DD * DD);
        int j = t & 31, q = t >> 5;
#pragma unroll
        for (int rr = 0; rr < 4; ++rr) {
            int row = q + rr * 8;
            tile[row][j] = W[(size_t)(k0 + row) * DD + c0 + j];
        }
        __syncthreads();
#pragma unroll
        for (int rr = 0; rr < 4; ++rr) {
            int cr = q + rr * 8;
            wt[(size_t)mat * DD * DD + (size_t)(c0 + cr) * DD + k0 + j] = (short)f2b(tile[j][cr]);
        }
    } else if (bid < B_SCAT + B_COMBO + B_WT + B_CVT) {
        // pure stream: x (fp32) -> xb (bf16), 8 elems/thread
        int gid = (bid - (B_SCAT + B_COMBO + B_WT)) * 256 + t;
        const float4* xp = (const float4*)(x + (size_t)gid * 8);
        float4 a = xp[0], c4 = xp[1];
        uint4 o;
        o.x = pk2(a.x, a.y); o.y = pk2(a.z, a.w);
        o.z = pk2(c4.x, c4.y); o.w = pk2(c4.z, c4.w);
        ((uint4*)xb4)[gid] = o;
    } else {
        // pool0: per-graph contiguous row-sum of fp32 x. 8 blocks/graph; rows
        // found by wave-uniform binary search on sorted batch; one LDS-reduced
        // atomicAdd per column per block (262K atomics total, overlapped by stripe).
        __shared__ float sm[DD];
        int b = bid - (B_SCAT + B_COMBO + B_WT + B_CVT);
        int g = b >> 3, s = b & 7;
        int r0, r1;
        {
            int lo = 0, hi = NN;
            while (lo < hi) { int m = (lo + hi) >> 1; if (batch[m] < g) lo = m + 1; else hi = m; }
            r0 = lo;
            lo = 0; hi = NN;
            while (lo < hi) { int m = (lo + hi) >> 1; if (batch[m] < g + 1) lo = m + 1; else hi = m; }
            r1 = lo;
        }
        int col = t & 127, par = t >> 7;
        float ssum = 0.f;
        for (int r = r0 + s * 2 + par; r < r1; r += 16) ssum += x[(size_t)r * DD + col];
        if (par == 0) sm[col] = ssum;
        __syncthreads();
        if (par == 1) {
            float v = sm[col] + ssum;
            if (v != 0.f) atomicAdd(&pooled0[(size_t)g * DD + col], v);
        }
    }
}

// ====== fused layer: CSR aggregation (phase A) + conv/BN/pool (phase B) ======
// Phase A: 4 waves x 8 nodes each; per node the wave's 16-lane x 8-feat gather
// computes hrow = x[node] + sum relu(x[src]+combo[cidx]) and writes it as bf16
// DIRECTLY into the LDS As tile (no hin global round-trip, no extra kernel).
// Phase B: identical to previous conv_fused (2x MFMA GEMM + BN + pool epilogue),
// writing the layer output to xout (ping-pong buffer; in-place is now a race).
__launch_bounds__(256)
__global__ void layer_fused(const unsigned short* __restrict__ xin,
                            const int* __restrict__ epos,
                            const unsigned* __restrict__ e_info,
                            const unsigned short* __restrict__ combo,
                            const short* __restrict__ Wt1, const short* __restrict__ Wt2,
                            const float* __restrict__ b1, const float* __restrict__ g1,
                            const float* __restrict__ be1, const float* __restrict__ m1,
                            const float* __restrict__ v1,
                            const float* __restrict__ b2, const float* __restrict__ g2,
                            const float* __restrict__ be2, const float* __restrict__ m2,
                            const float* __restrict__ v2,
                            const int* __restrict__ batch,
                            unsigned short* __restrict__ xout,
                            float* __restrict__ pool_slot) {
    __shared__ short As[32 * 136];
    __shared__ int sbg[32];
    const int tid  = threadIdx.x;
    const int lane = tid & 63;
    const int wave = tid >> 6;
    const int row0 = blockIdx.x * 32;
    const int gmin = batch[row0];

    if (tid < 32) {
        int row = row0 + tid;
        sbg[tid] = (row < NN) ? batch[row] - gmin : -1;
    }

    // ---- phase A: aggregation, 8 nodes per wave ----
    const int eg = lane >> 4;            // edge sub-group 0..3
    const int f  = (lane & 15) * 8;      // feature offset
    for (int k = 0; k < 8; ++k) {
        const int nl = wave * 8 + k;
        const int node = row0 + nl;
        if (node < NN) {
            const int base = node * ESTRIDE;
            unsigned i0 = __builtin_nontemporal_load(e_info + base + eg);
            unsigned i1 = __builtin_nontemporal_load(e_info + base + 4 + eg);
            unsigned i2 = __builtin_nontemporal_load(e_info + base + 8 + eg);
            unsigned i3 = __builtin_nontemporal_load(e_info + base + 12 + eg);

            uint4 xv0 = *(const uint4*)&xin[(size_t)(i0 & 0xFFFFu) * DD + f];
            uint4 cv0 = *(const uint4*)&combo[(size_t)(i0 >> 16) * DD + f];
            uint4 xv1 = *(const uint4*)&xin[(size_t)(i1 & 0xFFFFu) * DD + f];
            uint4 cv1 = *(const uint4*)&combo[(size_t)(i1 >> 16) * DD + f];
            uint4 xv2 = *(const uint4*)&xin[(size_t)(i2 & 0xFFFFu) * DD + f];
            uint4 cv2 = *(const uint4*)&combo[(size_t)(i2 >> 16) * DD + f];
            uint4 xv3 = *(const uint4*)&xin[(size_t)(i3 & 0xFFFFu) * DD + f];
            uint4 cv3 = *(const uint4*)&combo[(size_t)(i3 >> 16) * DD + f];

            float acc[8];
#pragma unroll
            for (int i = 0; i < 8; ++i) acc[i] = 0.f;
            acc8(acc, xv0, cv0);
            acc8(acc, xv1, cv1);
            acc8(acc, xv2, cv2);
            acc8(acc, xv3, cv3);

            int deg = epos[node];
            if (deg > 16) {              // ~10% of nodes; P(deg>24)~6e-4
                if (deg > ESTRIDE) deg = ESTRIDE;
                const int pe = base + ((deg + 7) & ~7);
                for (int p = base + 16; p < pe; p += 8) {
                    unsigned j0 = __builtin_nontemporal_load(e_info + p + eg);
                    unsigned j1 = __builtin_nontemporal_load(e_info + p + 4 + eg);
                    uint4 ax0 = *(const uint4*)&xin[(size_t)(j0 & 0xFFFFu) * DD + f];
                    uint4 ac0 = *(const uint4*)&combo[(size_t)(j0 >> 16) * DD + f];
                    uint4 ax1 = *(const uint4*)&xin[(size_t)(j1 & 0xFFFFu) * DD + f];
                    uint4 ac1 = *(const uint4*)&combo[(size_t)(j1 >> 16) * DD + f];
                    acc8(acc, ax0, ac0);
                    acc8(acc, ax1, ac1);
                }
            }

            // reduce across the 4 edge sub-groups (lanes differing in bits 4,5)
#pragma unroll
            for (int i = 0; i < 8; ++i) {
                acc[i] += __shfl_xor(acc[i], 16, 64);
                acc[i] += __shfl_xor(acc[i], 32, 64);
            }
            if (lane < 16) {
                uint4 self = *(const uint4*)&xin[(size_t)node * DD + f];
                uint4 o;
                o.x = pk2(acc[0] + blo(self.x), acc[1] + bhi(self.x));
                o.y = pk2(acc[2] + blo(self.y), acc[3] + bhi(self.y));
                o.z = pk2(acc[4] + blo(self.z), acc[5] + bhi(self.z));
                o.w = pk2(acc[6] + blo(self.w), acc[7] + bhi(self.w));
                *(uint4*)&As[nl * 136 + f] = o;
            }
        } else if (lane < 16) {
            *(uint4*)&As[nl * 136 + f] = make_uint4(0, 0, 0, 0);
        }
    }
    __syncthreads();

    // ---- phase B: conv + BN + pooling (reads As) ----
    const int col   = wave * 32 + (lane & 31);
    const int khalf = (lane >> 5) * 8;
    const int arow  = lane & 31;
    const int rbase = 4 * (lane >> 5);

    short8 bf[8];
#pragma unroll
    for (int ch = 0; ch < 8; ++ch)
        bf[ch] = *(const short8*)&Wt1[col * DD + ch * 16 + khalf];

    const float sc1 = g1[col] * rsqrtf(v1[col] + BN_EPS);
    const float sh1 = fmaf(b1[col] - m1[col], sc1, be1[col]);
    const float sc2 = g2[col] * rsqrtf(v2[col] + BN_EPS);
    const float sh2 = fmaf(b2[col] - m2[col], sc2, be2[col]);

    float16 acc0 = {0.f,0.f,0.f,0.f,0.f,0.f,0.f,0.f,0.f,0.f,0.f,0.f,0.f,0.f,0.f,0.f};
#pragma unroll
    for (int ch = 0; ch < 8; ++ch) {
        short8 a0 = *(const short8*)&As[arow * 136 + ch * 16 + khalf];
        acc0 = __builtin_amdgcn_mfma_f32_32x32x16_bf16(a0, bf[ch], acc0, 0, 0, 0);
    }

#pragma unroll
    for (int ch = 0; ch < 8; ++ch)
        bf[ch] = *(const short8*)&Wt2[col * DD + ch * 16 + khalf];

    __syncthreads();
#pragma unroll
    for (int r = 0; r < 16; ++r) {
        int rl = (r & 3) + 8 * (r >> 2) + rbase;
        As[rl * 136 + col] = (short)f2b(fmaxf(fmaf(acc0[r], sc1, sh1), 0.f));
    }
    __syncthreads();

    acc0 = float16{0.f,0.f,0.f,0.f,0.f,0.f,0.f,0.f,0.f,0.f,0.f,0.f,0.f,0.f,0.f,0.f};
#pragma unroll
    for (int ch = 0; ch < 8; ++ch) {
        short8 a0 = *(const short8*)&As[arow * 136 + ch * 16 + khalf];
        acc0 = __builtin_amdgcn_mfma_f32_32x32x16_bf16(a0, bf[ch], acc0, 0, 0, 0);
    }

    float pg0 = 0.f, pg1 = 0.f, pg2 = 0.f, pg3 = 0.f;
#pragma unroll
    for (int r = 0; r < 16; ++r) {
        int rl  = (r & 3) + 8 * (r >> 2) + rbase;
        int row = row0 + rl;
        float v0 = fmaxf(fmaf(acc0[r], sc2, sh2), 0.f);
        if (row < NN) xout[(size_t)row * DD + col] = f2b(v0);
        int ga = sbg[rl];
        pg0 += (ga == 0) ? v0 : 0.f;
        pg1 += (ga == 1) ? v0 : 0.f;
        pg2 += (ga == 2) ? v0 : 0.f;
        pg3 += (ga == 3) ? v0 : 0.f;
    }
    pg0 += __shfl_down(pg0, 32);
    pg1 += __shfl_down(pg1, 32);
    pg2 += __shfl_down(pg2, 32);
    pg3 += __shfl_down(pg3, 32);
    if (lane < 32) {
        if (pg0 != 0.f)                  atomicAdd(&pool_slot[(gmin    ) * DD + col], pg0);
        if (pg1 != 0.f && gmin + 1 < GG) atomicAdd(&pool_slot[(gmin + 1) * DD + col], pg1);
        if (pg2 != 0.f && gmin + 2 < GG) atomicAdd(&pool_slot[(gmin + 2) * DD + col], pg2);
        if (pg3 != 0.f && gmin + 3 < GG) atomicAdd(&pool_slot[(gmin + 3) * DD + col], pg3);
    }
}

// ====== final head: out[g,:] = inv[g]*sum_l pooled_l@fcw_l + sum_l fcb_l ======
__launch_bounds__(64)
__global__ void head(const int* __restrict__ batch, const float* __restrict__ pooled,
                     const float* __restrict__ fcw, const float* __restrict__ fcb,
                     float* __restrict__ out) {
    int g = blockIdx.x, t = threadIdx.x;
    __shared__ float part[LL + 1][OO];
    // wave-uniform binary searches on sorted batch -> graph size
    int r0, r1;
    {
        int lo = 0, hi = NN;
        while (lo < hi) { int m = (lo + hi) >> 1; if (batch[m] < g) lo = m + 1; else hi = m; }
        r0 = lo;
        lo = 0; hi = NN;
        while (lo < hi) { int m = (lo + hi) >> 1; if (batch[m] < g + 1) lo = m + 1; else hi = m; }
        r1 = lo;
    }
    const float invg = 1.0f / fmaxf((float)(r1 - r0), 1.0f);
    if (t < (LL + 1) * OO) {
        int l = t / OO, o2 = t - l * OO;
        const float* p = pooled + ((size_t)l * GG + g) * DD;
        const float* w = fcw + (size_t)l * DD * OO + o2;
        float s = 0.f;
        for (int d2 = 0; d2 < DD; ++d2) s = fmaf(p[d2], w[(size_t)d2 * OO], s);
        part[l][o2] = s;
    }
    __syncthreads();
    if (t < OO) {
        float sp = 0.f, sb2 = 0.f;
#pragma unroll
        for (int l = 0; l < LL + 1; ++l) { sp += part[l][t]; sb2 += fcb[l * OO + t]; }
        out[g * OO + t] = sp * invg + sb2;
    }
}

extern "C" void kernel_launch(void* const* d_in, const int* in_sizes, int n_in,
                              void* d_out, int out_size, void* d_ws, size_t ws_size,
                              hipStream_t stream) {
    const float* x_in    = (const float*)d_in[0];
    const int*   ei      = (const int*)d_in[1];
    const int*   eattr   = (const int*)d_in[2];
    const int*   batch   = (const int*)d_in[3];
    const float* bond    = (const float*)d_in[4];
    const float* conv_w1 = (const float*)d_in[5];
    const float* conv_b1 = (const float*)d_in[6];
    const float* cbg     = (const float*)d_in[7];
    const float* cbb     = (const float*)d_in[8];
    const float* cbm     = (const float*)d_in[9];
    const float* cbv     = (const float*)d_in[10];
    const float* conv_w2 = (const float*)d_in[11];
    const float* conv_b2 = (const float*)d_in[12];
    const float* bg      = (const float*)d_in[13];
    const float* bb      = (const float*)d_in[14];
    const float* bm      = (const float*)d_in[15];
    const float* bv      = (const float*)d_in[16];
    const float* fcw     = (const float*)d_in[17];
    const float* fcb     = (const float*)d_in[18];
    float* out = (float*)d_out;

    // ---- workspace carve-up (16B-aligned chunks) ----
    char* base = (char*)d_ws;
    size_t o = 0;
    auto carve = [&](size_t bytes) { void* p = base + o; o += (bytes + 15) & ~(size_t)15; return p; };
    unsigned short* xbA    = (unsigned short*)carve((size_t)NN * DD * 2);
    unsigned short* xbB    = (unsigned short*)carve((size_t)NN * DD * 2);
    unsigned short* combo  = (unsigned short*)carve((size_t)LL * CPAD * DD * 2);
    short*          wt     = (short*)carve((size_t)10 * DD * DD * 2);
    // contiguous zero-region: epos | pooled[6][G][D] (slot 0 = pool0)
    const size_t ZBYTES = (size_t)NN * 4 + (size_t)(LL + 1) * GG * DD * 4;
    int*            epos   = (int*)carve(ZBYTES);
    float*          pooled = (float*)((char*)epos + (size_t)NN * 4);
    unsigned*       e_info = (unsigned*)carve((size_t)NN * ESTRIDE * 4);

    hipMemsetAsync(epos, 0, ZBYTES, stream);
    hipMemsetAsync(e_info, 0x02, (size_t)NN * ESTRIDE * 4, stream);   // sentinel fill

    prep<<<B_PREP, 256, 0, stream>>>(x_in, ei, eattr, batch, bond, conv_w1, conv_w2,
                                     (unsigned*)xbA, combo, wt, epos, e_info, pooled);

    const int layer_blocks = (NN + 31) / 32;    // 1563
    unsigned short* xcur = xbA;   // layer input (complete previous activation)
    unsigned short* xnxt = xbB;   // layer output (ping-pong; in-place would race)
    for (int i = 0; i < LL; ++i) {
        layer_fused<<<layer_blocks, 256, 0, stream>>>(
            xcur, epos, e_info, combo + (size_t)i * CPAD * DD,
            wt + (size_t)i * DD * DD, wt + (size_t)(5 + i) * DD * DD,
            conv_b1 + (size_t)i * DD, cbg + (size_t)i * DD, cbb + (size_t)i * DD,
            cbm + (size_t)i * DD, cbv + (size_t)i * DD,
            conv_b2 + (size_t)i * DD, bg + (size_t)i * DD, bb + (size_t)i * DD,
            bm + (size_t)i * DD, bv + (size_t)i * DD,
            batch, xnxt, pooled + (size_t)(i + 1) * GG * DD);
        unsigned short* tmp = xcur; xcur = xnxt; xnxt = tmp;
    }
    head<<<GG, 64, 0, stream>>>(batch, pooled, fcw, fcb, out);
}

// Round 8
// 405.049 us; speedup vs baseline: 1.0611x; 1.0611x over previous
//
#include <hip/hip_runtime.h>

#define NN 50000
#define EE 600000
#define DD 128
#define GG 256
#define LL 5
#define OO 10
#define BN_EPS 1e-5f
#define CPAD 515      // 512 combos + 3 sentinel (-1e30) rows (slot 0x02020202 -> cidx 514)
#define ESTRIDE 40    // fixed CSR slots per node (P(deg>40)~1e-9 at lambda=12)

// prep kernel block-range sizes (virtual ids; physical blocks are striped through
// all sections via a bijective mod-permutation so latency-bound atomic work
// overlaps BW-bound streaming work instead of running as serial phases)
#define B_SCAT  2344                       // ceil(EE/256)
#define B_COMBO 1288                       // ceil(LL*CPAD*DD / 256)
#define B_WT    160                        // 10 mats x 16 (32x32) tiles
#define B_CVT   3125                       // NN*DD/8 / 256 (pure convert)
#define B_POOL  2048                       // 8 blocks per graph
#define B_PREP  (B_SCAT + B_COMBO + B_WT + B_CVT + B_POOL)  // 8965 = 5*11*163, coprime w/ 1021

typedef __attribute__((ext_vector_type(8))) short short8;
typedef __attribute__((ext_vector_type(16))) float float16;
typedef __attribute__((ext_vector_type(4))) unsigned uint4e;   // nontemporal-compatible

__device__ __forceinline__ unsigned short f2b(float f) {   // fp32 -> bf16 RNE
    unsigned u = __float_as_uint(f);
    unsigned r = u + 0x7FFFu + ((u >> 16) & 1u);
    return (unsigned short)(r >> 16);
}
__device__ __forceinline__ unsigned pk2(float lo, float hi) {
    return (unsigned)f2b(lo) | ((unsigned)f2b(hi) << 16);
}
__device__ __forceinline__ float blo(unsigned u) { return __uint_as_float(u << 16); }
__device__ __forceinline__ float bhi(unsigned u) { return __uint_as_float(u & 0xFFFF0000u); }

__device__ __forceinline__ void acc8(float* acc, uint4 xv, uint4 cv) {
    acc[0] += fmaxf(blo(xv.x) + blo(cv.x), 0.f);
    acc[1] += fmaxf(bhi(xv.x) + bhi(cv.x), 0.f);
    acc[2] += fmaxf(blo(xv.y) + blo(cv.y), 0.f);
    acc[3] += fmaxf(bhi(xv.y) + bhi(cv.y), 0.f);
    acc[4] += fmaxf(blo(xv.z) + blo(cv.z), 0.f);
    acc[5] += fmaxf(bhi(xv.z) + bhi(cv.z), 0.f);
    acc[6] += fmaxf(blo(xv.w) + blo(cv.w), 0.f);
    acc[7] += fmaxf(bhi(xv.w) + bhi(cv.w), 0.f);
}

// == mega prep: edge-scatter | combo | Wt-transpose | cvt_x | pool0 (striped) ==
__launch_bounds__(256)
__global__ void prep(const float* __restrict__ x, const int* __restrict__ ei,
                     const int* __restrict__ eattr, const int* __restrict__ batch,
                     const float* __restrict__ bond,
                     const float* __restrict__ w1, const float* __restrict__ w2,
                     unsigned* __restrict__ xb4, unsigned short* __restrict__ combo,
                     short* __restrict__ wt, int* __restrict__ epos,
                     unsigned* __restrict__ e_info, float* __restrict__ pooled0) {
    // bijective stripe: gcd(1021, 8965)=1 -> all sections co-resident
    const int bid = (int)(((long long)blockIdx.x * 1021) % B_PREP);
    const int t = threadIdx.x;
    if (bid < B_SCAT) {
        // scatter edges into fixed-stride CSR. Deps: epos==0, e_info==0x02020202
        // (both memset before launch). Unfilled slots stay = sentinel.
        int e = bid * 256 + t;
        if (e < EE) {
            int dst = ei[EE + e];
            int slot = atomicAdd(&epos[dst], 1);
            if (slot < ESTRIDE) {
                unsigned cidx = (unsigned)eattr[e * 3 + 0] | ((unsigned)eattr[e * 3 + 1] << 3)
                              | ((unsigned)eattr[e * 3 + 2] << 6);
                e_info[dst * ESTRIDE + slot] = (unsigned)ei[e] | (cidx << 16);
            }
        }
    } else if (bid < B_SCAT + B_COMBO) {
        int e = (bid - B_SCAT) * 256 + t;
        if (e < LL * CPAD * DD) {
            int l = e / (CPAD * DD), rem = e - l * (CPAD * DD);
            int c = rem / DD, d = rem - c * DD;
            float s;
            if (c >= 512) s = -1e30f;                     // sentinel rows: relu(x+s)==0
            else {
                const float* b_ = bond + (size_t)l * 3 * 8 * DD;
                s = b_[(c & 7) * DD + d] + b_[(8 + ((c >> 3) & 7)) * DD + d]
                  + b_[(16 + (c >> 6)) * DD + d];
            }
            combo[e] = f2b(s);
        }
    } else if (bid < B_SCAT + B_COMBO + B_WT) {
        // coalesced transpose: wt[mat][c][k] = bf16(W[mat][k][c]), 32x32 LDS tiles
        __shared__ float tile[32][33];
        int b = bid - B_SCAT - B_COMBO;
        int mat = b >> 4, tl = b & 15;
        int k0 = (tl >> 2) * 32, c0 = (tl & 3) * 32;
        const float* W = (mat < 5) ? (w1 + (size_t)mat * DD * DD)
                                   : (w2 + (size_t)(mat - 5) * DD * DD);
        int j = t & 31, q = t >> 5;
#pragma unroll
        for (int rr = 0; rr < 4; ++rr) {
            int row = q + rr * 8;
            tile[row][j] = W[(size_t)(k0 + row) * DD + c0 + j];
        }
        __syncthreads();
#pragma unroll
        for (int rr = 0; rr < 4; ++rr) {
            int cr = q + rr * 8;
            wt[(size_t)mat * DD * DD + (size_t)(c0 + cr) * DD + k0 + j] = (short)f2b(tile[j][cr]);
        }
    } else if (bid < B_SCAT + B_COMBO + B_WT + B_CVT) {
        // pure stream: x (fp32) -> xb (bf16), 8 elems/thread
        int gid = (bid - (B_SCAT + B_COMBO + B_WT)) * 256 + t;
        const float4* xp = (const float4*)(x + (size_t)gid * 8);
        float4 a = xp[0], c4 = xp[1];
        uint4 o;
        o.x = pk2(a.x, a.y); o.y = pk2(a.z, a.w);
        o.z = pk2(c4.x, c4.y); o.w = pk2(c4.z, c4.w);
        ((uint4*)xb4)[gid] = o;
    } else {
        // pool0: per-graph contiguous row-sum of fp32 x. 8 blocks/graph; rows
        // found by wave-uniform binary search on sorted batch; one LDS-reduced
        // atomicAdd per column per block (262K atomics total, overlapped by stripe).
        __shared__ float sm[DD];
        int b = bid - (B_SCAT + B_COMBO + B_WT + B_CVT);
        int g = b >> 3, s = b & 7;
        int r0, r1;
        {
            int lo = 0, hi = NN;
            while (lo < hi) { int m = (lo + hi) >> 1; if (batch[m] < g) lo = m + 1; else hi = m; }
            r0 = lo;
            lo = 0; hi = NN;
            while (lo < hi) { int m = (lo + hi) >> 1; if (batch[m] < g + 1) lo = m + 1; else hi = m; }
            r1 = lo;
        }
        int col = t & 127, par = t >> 7;
        float ssum = 0.f;
        for (int r = r0 + s * 2 + par; r < r1; r += 16) ssum += x[(size_t)r * DD + col];
        if (par == 0) sm[col] = ssum;
        __syncthreads();
        if (par == 1) {
            float v = sm[col] + ssum;
            if (v != 0.f) atomicAdd(&pooled0[(size_t)g * DD + col], v);
        }
    }
}

// ====== fused layer: CSR aggregation (phase A) + conv/BN/pool (phase B) ======
// Phase A (MLP-restructured): per wave, e_info for all 8 owned nodes is
// prefetched up front as one dwordx4 each (lane's 4 slots = consecutive
// {4eg..4eg+3}; sum is commutative so the lane->slot map is free), and deg for
// all 8 nodes via one lane-parallel load + shfl. Gathers of node k+1 depend
// only on resident ev[k+1] -> cross-node overlap; the per-node
// e_info->gather serial round-trip is gone.
__launch_bounds__(256, 4)
__global__ void layer_fused(const unsigned short* __restrict__ xin,
                            const int* __restrict__ epos,
                            const unsigned* __restrict__ e_info,
                            const unsigned short* __restrict__ combo,
                            const short* __restrict__ Wt1, const short* __restrict__ Wt2,
                            const float* __restrict__ b1, const float* __restrict__ g1,
                            const float* __restrict__ be1, const float* __restrict__ m1,
                            const float* __restrict__ v1,
                            const float* __restrict__ b2, const float* __restrict__ g2,
                            const float* __restrict__ be2, const float* __restrict__ m2,
                            const float* __restrict__ v2,
                            const int* __restrict__ batch,
                            unsigned short* __restrict__ xout,
                            float* __restrict__ pool_slot) {
    __shared__ short As[32 * 136];
    __shared__ int sbg[32];
    const int tid  = threadIdx.x;
    const int lane = tid & 63;
    const int wave = tid >> 6;
    const int row0 = blockIdx.x * 32;
    const int gmin = batch[row0];

    if (tid < 32) {
        int row = row0 + tid;
        sbg[tid] = (row < NN) ? batch[row] - gmin : -1;
    }

    // ---- phase A ----
    const int eg = lane >> 4;            // slot sub-group 0..3
    const int f  = (lane & 15) * 8;      // feature offset
    const int node0 = row0 + wave * 8;

    // deg prefetch: lane j holds epos[node0 + (j&7)]
    int degp;
    {
        int nk = node0 + (lane & 7);
        if (nk >= NN) nk = NN - 1;
        degp = epos[nk];
    }
    // e_info prefetch: one dwordx4 per node (this lane's slots {4eg..4eg+3})
    uint4e ev[8];
#pragma unroll
    for (int k = 0; k < 8; ++k) {
        int nk = node0 + k;
        if (nk >= NN) nk = NN - 1;
        ev[k] = __builtin_nontemporal_load(
            (const uint4e*)&e_info[(size_t)nk * ESTRIDE + eg * 4]);
    }

#pragma unroll
    for (int k = 0; k < 8; ++k) {
        const int nl = wave * 8 + k;
        const int node = row0 + nl;
        if (node < NN) {
            uint4 xv0 = *(const uint4*)&xin[(size_t)(ev[k].x & 0xFFFFu) * DD + f];
            uint4 cv0 = *(const uint4*)&combo[(size_t)(ev[k].x >> 16) * DD + f];
            uint4 xv1 = *(const uint4*)&xin[(size_t)(ev[k].y & 0xFFFFu) * DD + f];
            uint4 cv1 = *(const uint4*)&combo[(size_t)(ev[k].y >> 16) * DD + f];
            uint4 xv2 = *(const uint4*)&xin[(size_t)(ev[k].z & 0xFFFFu) * DD + f];
            uint4 cv2 = *(const uint4*)&combo[(size_t)(ev[k].z >> 16) * DD + f];
            uint4 xv3 = *(const uint4*)&xin[(size_t)(ev[k].w & 0xFFFFu) * DD + f];
            uint4 cv3 = *(const uint4*)&combo[(size_t)(ev[k].w >> 16) * DD + f];

            float acc[8];
#pragma unroll
            for (int i = 0; i < 8; ++i) acc[i] = 0.f;
            acc8(acc, xv0, cv0);
            acc8(acc, xv1, cv1);
            acc8(acc, xv2, cv2);
            acc8(acc, xv3, cv3);

            int deg = __shfl(degp, k, 64);
            if (deg > 16) {              // ~10% of nodes; P(deg>24)~6e-4
                if (deg > ESTRIDE) deg = ESTRIDE;
                const int base = node * ESTRIDE;
                const int pe = base + ((deg + 7) & ~7);
                for (int p = base + 16; p < pe; p += 8) {
                    // 8 slots; this lane takes {p+2eg, p+2eg+1}
                    uint2 jv = *(const uint2*)&e_info[p + eg * 2];
                    uint4 ax0 = *(const uint4*)&xin[(size_t)(jv.x & 0xFFFFu) * DD + f];
                    uint4 ac0 = *(const uint4*)&combo[(size_t)(jv.x >> 16) * DD + f];
                    uint4 ax1 = *(const uint4*)&xin[(size_t)(jv.y & 0xFFFFu) * DD + f];
                    uint4 ac1 = *(const uint4*)&combo[(size_t)(jv.y >> 16) * DD + f];
                    acc8(acc, ax0, ac0);
                    acc8(acc, ax1, ac1);
                }
            }

            // reduce across the 4 slot sub-groups (lanes differing in bits 4,5)
#pragma unroll
            for (int i = 0; i < 8; ++i) {
                acc[i] += __shfl_xor(acc[i], 16, 64);
                acc[i] += __shfl_xor(acc[i], 32, 64);
            }
            if (lane < 16) {
                uint4 self = *(const uint4*)&xin[(size_t)node * DD + f];
                uint4 o;
                o.x = pk2(acc[0] + blo(self.x), acc[1] + bhi(self.x));
                o.y = pk2(acc[2] + blo(self.y), acc[3] + bhi(self.y));
                o.z = pk2(acc[4] + blo(self.z), acc[5] + bhi(self.z));
                o.w = pk2(acc[6] + blo(self.w), acc[7] + bhi(self.w));
                *(uint4*)&As[nl * 136 + f] = o;
            }
        } else if (lane < 16) {
            *(uint4*)&As[nl * 136 + f] = make_uint4(0, 0, 0, 0);
        }
    }
    __syncthreads();

    // ---- phase B: conv + BN + pooling (reads As) ----
    const int col   = wave * 32 + (lane & 31);
    const int khalf = (lane >> 5) * 8;
    const int arow  = lane & 31;
    const int rbase = 4 * (lane >> 5);

    short8 bf[8];
#pragma unroll
    for (int ch = 0; ch < 8; ++ch)
        bf[ch] = *(const short8*)&Wt1[col * DD + ch * 16 + khalf];

    const float sc1 = g1[col] * rsqrtf(v1[col] + BN_EPS);
    const float sh1 = fmaf(b1[col] - m1[col], sc1, be1[col]);
    const float sc2 = g2[col] * rsqrtf(v2[col] + BN_EPS);
    const float sh2 = fmaf(b2[col] - m2[col], sc2, be2[col]);

    float16 acc0 = {0.f,0.f,0.f,0.f,0.f,0.f,0.f,0.f,0.f,0.f,0.f,0.f,0.f,0.f,0.f,0.f};
#pragma unroll
    for (int ch = 0; ch < 8; ++ch) {
        short8 a0 = *(const short8*)&As[arow * 136 + ch * 16 + khalf];
        acc0 = __builtin_amdgcn_mfma_f32_32x32x16_bf16(a0, bf[ch], acc0, 0, 0, 0);
    }

#pragma unroll
    for (int ch = 0; ch < 8; ++ch)
        bf[ch] = *(const short8*)&Wt2[col * DD + ch * 16 + khalf];

    __syncthreads();
#pragma unroll
    for (int r = 0; r < 16; ++r) {
        int rl = (r & 3) + 8 * (r >> 2) + rbase;
        As[rl * 136 + col] = (short)f2b(fmaxf(fmaf(acc0[r], sc1, sh1), 0.f));
    }
    __syncthreads();

    acc0 = float16{0.f,0.f,0.f,0.f,0.f,0.f,0.f,0.f,0.f,0.f,0.f,0.f,0.f,0.f,0.f,0.f};
#pragma unroll
    for (int ch = 0; ch < 8; ++ch) {
        short8 a0 = *(const short8*)&As[arow * 136 + ch * 16 + khalf];
        acc0 = __builtin_amdgcn_mfma_f32_32x32x16_bf16(a0, bf[ch], acc0, 0, 0, 0);
    }

    float pg0 = 0.f, pg1 = 0.f, pg2 = 0.f, pg3 = 0.f;
#pragma unroll
    for (int r = 0; r < 16; ++r) {
        int rl  = (r & 3) + 8 * (r >> 2) + rbase;
        int row = row0 + rl;
        float v0 = fmaxf(fmaf(acc0[r], sc2, sh2), 0.f);
        if (row < NN) xout[(size_t)row * DD + col] = f2b(v0);
        int ga = sbg[rl];
        pg0 += (ga == 0) ? v0 : 0.f;
        pg1 += (ga == 1) ? v0 : 0.f;
        pg2 += (ga == 2) ? v0 : 0.f;
        pg3 += (ga == 3) ? v0 : 0.f;
    }
    pg0 += __shfl_down(pg0, 32);
    pg1 += __shfl_down(pg1, 32);
    pg2 += __shfl_down(pg2, 32);
    pg3 += __shfl_down(pg3, 32);
    if (lane < 32) {
        if (pg0 != 0.f)                  atomicAdd(&pool_slot[(gmin    ) * DD + col], pg0);
        if (pg1 != 0.f && gmin + 1 < GG) atomicAdd(&pool_slot[(gmin + 1) * DD + col], pg1);
        if (pg2 != 0.f && gmin + 2 < GG) atomicAdd(&pool_slot[(gmin + 2) * DD + col], pg2);
        if (pg3 != 0.f && gmin + 3 < GG) atomicAdd(&pool_slot[(gmin + 3) * DD + col], pg3);
    }
}

// ====== final head: out[g,:] = inv[g]*sum_l pooled_l@fcw_l + sum_l fcb_l ======
__launch_bounds__(64)
__global__ void head(const int* __restrict__ batch, const float* __restrict__ pooled,
                     const float* __restrict__ fcw, const float* __restrict__ fcb,
                     float* __restrict__ out) {
    int g = blockIdx.x, t = threadIdx.x;
    __shared__ float part[LL + 1][OO];
    // wave-uniform binary searches on sorted batch -> graph size
    int r0, r1;
    {
        int lo = 0, hi = NN;
        while (lo < hi) { int m = (lo + hi) >> 1; if (batch[m] < g) lo = m + 1; else hi = m; }
        r0 = lo;
        lo = 0; hi = NN;
        while (lo < hi) { int m = (lo + hi) >> 1; if (batch[m] < g + 1) lo = m + 1; else hi = m; }
        r1 = lo;
    }
    const float invg = 1.0f / fmaxf((float)(r1 - r0), 1.0f);
    if (t < (LL + 1) * OO) {
        int l = t / OO, o2 = t - l * OO;
        const float* p = pooled + ((size_t)l * GG + g) * DD;
        const float* w = fcw + (size_t)l * DD * OO + o2;
        float s = 0.f;
        for (int d2 = 0; d2 < DD; ++d2) s = fmaf(p[d2], w[(size_t)d2 * OO], s);
        part[l][o2] = s;
    }
    __syncthreads();
    if (t < OO) {
        float sp = 0.f, sb2 = 0.f;
#pragma unroll
        for (int l = 0; l < LL + 1; ++l) { sp += part[l][t]; sb2 += fcb[l * OO + t]; }
        out[g * OO + t] = sp * invg + sb2;
    }
}

extern "C" void kernel_launch(void* const* d_in, const int* in_sizes, int n_in,
                              void* d_out, int out_size, void* d_ws, size_t ws_size,
                              hipStream_t stream) {
    const float* x_in    = (const float*)d_in[0];
    const int*   ei      = (const int*)d_in[1];
    const int*   eattr   = (const int*)d_in[2];
    const int*   batch   = (const int*)d_in[3];
    const float* bond    = (const float*)d_in[4];
    const float* conv_w1 = (const float*)d_in[5];
    const float* conv_b1 = (const float*)d_in[6];
    const float* cbg     = (const float*)d_in[7];
    const float* cbb     = (const float*)d_in[8];
    const float* cbm     = (const float*)d_in[9];
    const float* cbv     = (const float*)d_in[10];
    const float* conv_w2 = (const float*)d_in[11];
    const float* conv_b2 = (const float*)d_in[12];
    const float* bg      = (const float*)d_in[13];
    const float* bb      = (const float*)d_in[14];
    const float* bm      = (const float*)d_in[15];
    const float* bv      = (const float*)d_in[16];
    const float* fcw     = (const float*)d_in[17];
    const float* fcb     = (const float*)d_in[18];
    float* out = (float*)d_out;

    // ---- workspace carve-up (16B-aligned chunks) ----
    char* base = (char*)d_ws;
    size_t o = 0;
    auto carve = [&](size_t bytes) { void* p = base + o; o += (bytes + 15) & ~(size_t)15; return p; };
    unsigned short* xbA    = (unsigned short*)carve((size_t)NN * DD * 2);
    unsigned short* xbB    = (unsigned short*)carve((size_t)NN * DD * 2);
    unsigned short* combo  = (unsigned short*)carve((size_t)LL * CPAD * DD * 2);
    short*          wt     = (short*)carve((size_t)10 * DD * DD * 2);
    // contiguous zero-region: epos | pooled[6][G][D] (slot 0 = pool0)
    const size_t ZBYTES = (size_t)NN * 4 + (size_t)(LL + 1) * GG * DD * 4;
    int*            epos   = (int*)carve(ZBYTES);
    float*          pooled = (float*)((char*)epos + (size_t)NN * 4);
    unsigned*       e_info = (unsigned*)carve((size_t)NN * ESTRIDE * 4);

    (void)hipMemsetAsync(epos, 0, ZBYTES, stream);
    (void)hipMemsetAsync(e_info, 0x02, (size_t)NN * ESTRIDE * 4, stream);  // sentinel fill

    prep<<<B_PREP, 256, 0, stream>>>(x_in, ei, eattr, batch, bond, conv_w1, conv_w2,
                                     (unsigned*)xbA, combo, wt, epos, e_info, pooled);

    const int layer_blocks = (NN + 31) / 32;    // 1563
    unsigned short* xcur = xbA;   // layer input (complete previous activation)
    unsigned short* xnxt = xbB;   // layer output (ping-pong; in-place would race)
    for (int i = 0; i < LL; ++i) {
        layer_fused<<<layer_blocks, 256, 0, stream>>>(
            xcur, epos, e_info, combo + (size_t)i * CPAD * DD,
            wt + (size_t)i * DD * DD, wt + (size_t)(5 + i) * DD * DD,
            conv_b1 + (size_t)i * DD, cbg + (size_t)i * DD, cbb + (size_t)i * DD,
            cbm + (size_t)i * DD, cbv + (size_t)i * DD,
            conv_b2 + (size_t)i * DD, bg + (size_t)i * DD, bb + (size_t)i * DD,
            bm + (size_t)i * DD, bv + (size_t)i * DD,
            batch, xnxt, pooled + (size_t)(i + 1) * GG * DD);
        unsigned short* tmp = xcur; xcur = xnxt; xnxt = tmp;
    }
    head<<<GG, 64, 0, stream>>>(batch, pooled, fcw, fcb, out);
}

// Round 9
// 393.990 us; speedup vs baseline: 1.0909x; 1.0281x over previous
//
#include <hip/hip_runtime.h>

#define NN 50000
#define EE 600000
#define DD 128
#define GG 256
#define LL 5
#define OO 10
#define BN_EPS 1e-5f
#define CPAD 515      // 512 combos + 3 sentinel (-1e30) rows (slot 0x02020202 -> cidx 514)
#define ESTRIDE 40    // fixed CSR slots per node (P(deg>40)~1e-9 at lambda=12)

// prep kernel block-range sizes (virtual ids; physical blocks are striped through
// all sections via a bijective mod-permutation so latency-bound atomic work
// overlaps BW-bound streaming work instead of running as serial phases)
#define B_SCAT  2344                       // ceil(EE/256)
#define B_COMBO 1288                       // ceil(LL*CPAD*DD / 256)
#define B_WT    160                        // 10 mats x 16 (32x32) tiles
#define B_CVT   3125                       // NN*DD/8 / 256 (pure convert)
#define B_POOL  2048                       // 8 blocks per graph
#define B_PREP  (B_SCAT + B_COMBO + B_WT + B_CVT + B_POOL)  // 8965 = 5*11*163, coprime w/ 1021

typedef __attribute__((ext_vector_type(8))) short short8;
typedef __attribute__((ext_vector_type(16))) float float16;
typedef __attribute__((ext_vector_type(4))) unsigned uint4e;   // nontemporal-compatible

__device__ __forceinline__ unsigned short f2b(float f) {   // fp32 -> bf16 RNE
    unsigned u = __float_as_uint(f);
    unsigned r = u + 0x7FFFu + ((u >> 16) & 1u);
    return (unsigned short)(r >> 16);
}
__device__ __forceinline__ unsigned pk2(float lo, float hi) {
    return (unsigned)f2b(lo) | ((unsigned)f2b(hi) << 16);
}
__device__ __forceinline__ float blo(unsigned u) { return __uint_as_float(u << 16); }
__device__ __forceinline__ float bhi(unsigned u) { return __uint_as_float(u & 0xFFFF0000u); }

__device__ __forceinline__ void acc8(float* acc, uint4 xv, uint4 cv) {
    acc[0] += fmaxf(blo(xv.x) + blo(cv.x), 0.f);
    acc[1] += fmaxf(bhi(xv.x) + bhi(cv.x), 0.f);
    acc[2] += fmaxf(blo(xv.y) + blo(cv.y), 0.f);
    acc[3] += fmaxf(bhi(xv.y) + bhi(cv.y), 0.f);
    acc[4] += fmaxf(blo(xv.z) + blo(cv.z), 0.f);
    acc[5] += fmaxf(bhi(xv.z) + bhi(cv.z), 0.f);
    acc[6] += fmaxf(blo(xv.w) + blo(cv.w), 0.f);
    acc[7] += fmaxf(bhi(xv.w) + bhi(cv.w), 0.f);
}

// == mega prep: edge-scatter | combo | Wt-transpose | cvt_x | pool0 (striped) ==
__launch_bounds__(256)
__global__ void prep(const float* __restrict__ x, const int* __restrict__ ei,
                     const int* __restrict__ eattr, const int* __restrict__ batch,
                     const float* __restrict__ bond,
                     const float* __restrict__ w1, const float* __restrict__ w2,
                     unsigned* __restrict__ xb4, unsigned short* __restrict__ combo,
                     short* __restrict__ wt, int* __restrict__ epos,
                     unsigned* __restrict__ e_info, float* __restrict__ pooled0) {
    // bijective stripe: gcd(1021, 8965)=1 -> all sections co-resident
    const int bid = (int)(((long long)blockIdx.x * 1021) % B_PREP);
    const int t = threadIdx.x;
    if (bid < B_SCAT) {
        // scatter edges into fixed-stride CSR. Deps: epos==0, e_info==0x02020202
        // (both memset before launch). Unfilled slots stay = sentinel.
        int e = bid * 256 + t;
        if (e < EE) {
            int dst = ei[EE + e];
            int slot = atomicAdd(&epos[dst], 1);
            if (slot < ESTRIDE) {
                unsigned cidx = (unsigned)eattr[e * 3 + 0] | ((unsigned)eattr[e * 3 + 1] << 3)
                              | ((unsigned)eattr[e * 3 + 2] << 6);
                e_info[dst * ESTRIDE + slot] = (unsigned)ei[e] | (cidx << 16);
            }
        }
    } else if (bid < B_SCAT + B_COMBO) {
        int e = (bid - B_SCAT) * 256 + t;
        if (e < LL * CPAD * DD) {
            int l = e / (CPAD * DD), rem = e - l * (CPAD * DD);
            int c = rem / DD, d = rem - c * DD;
            float s;
            if (c >= 512) s = -1e30f;                     // sentinel rows: relu(x+s)==0
            else {
                const float* b_ = bond + (size_t)l * 3 * 8 * DD;
                s = b_[(c & 7) * DD + d] + b_[(8 + ((c >> 3) & 7)) * DD + d]
                  + b_[(16 + (c >> 6)) * DD + d];
            }
            combo[e] = f2b(s);
        }
    } else if (bid < B_SCAT + B_COMBO + B_WT) {
        // coalesced transpose: wt[mat][c][k] = bf16(W[mat][k][c]), 32x32 LDS tiles
        __shared__ float tile[32][33];
        int b = bid - B_SCAT - B_COMBO;
        int mat = b >> 4, tl = b & 15;
        int k0 = (tl >> 2) * 32, c0 = (tl & 3) * 32;
        const float* W = (mat < 5) ? (w1 + (size_t)mat * DD * DD)
                                   : (w2 + (size_t)(mat - 5) * DD * DD);
        int j = t & 31, q = t >> 5;
#pragma unroll
        for (int rr = 0; rr < 4; ++rr) {
            int row = q + rr * 8;
            tile[row][j] = W[(size_t)(k0 + row) * DD + c0 + j];
        }
        __syncthreads();
#pragma unroll
        for (int rr = 0; rr < 4; ++rr) {
            int cr = q + rr * 8;
            wt[(size_t)mat * DD * DD + (size_t)(c0 + cr) * DD + k0 + j] = (short)f2b(tile[j][cr]);
        }
    } else if (bid < B_SCAT + B_COMBO + B_WT + B_CVT) {
        // pure stream: x (fp32) -> xb (bf16), 8 elems/thread
        int gid = (bid - (B_SCAT + B_COMBO + B_WT)) * 256 + t;
        const float4* xp = (const float4*)(x + (size_t)gid * 8);
        float4 a = xp[0], c4 = xp[1];
        uint4 o;
        o.x = pk2(a.x, a.y); o.y = pk2(a.z, a.w);
        o.z = pk2(c4.x, c4.y); o.w = pk2(c4.z, c4.w);
        ((uint4*)xb4)[gid] = o;
    } else {
        // pool0: per-graph contiguous row-sum of fp32 x. 8 blocks/graph; rows
        // found by wave-uniform binary search on sorted batch; one LDS-reduced
        // atomicAdd per column per block (262K atomics total, overlapped by stripe).
        __shared__ float sm[DD];
        int b = bid - (B_SCAT + B_COMBO + B_WT + B_CVT);
        int g = b >> 3, s = b & 7;
        int r0, r1;
        {
            int lo = 0, hi = NN;
            while (lo < hi) { int m = (lo + hi) >> 1; if (batch[m] < g) lo = m + 1; else hi = m; }
            r0 = lo;
            lo = 0; hi = NN;
            while (lo < hi) { int m = (lo + hi) >> 1; if (batch[m] < g + 1) lo = m + 1; else hi = m; }
            r1 = lo;
        }
        int col = t & 127, par = t >> 7;
        float ssum = 0.f;
        for (int r = r0 + s * 2 + par; r < r1; r += 16) ssum += x[(size_t)r * DD + col];
        if (par == 0) sm[col] = ssum;
        __syncthreads();
        if (par == 1) {
            float v = sm[col] + ssum;
            if (v != 0.f) atomicAdd(&pooled0[(size_t)g * DD + col], v);
        }
    }
}

// ====== fused layer: CSR aggregation (phase A) + conv/BN/pool (phase B) ======
// Phase A: manual 2-deep software pipeline. ev[8] prefetched up front; the 8
// gathers (4 xin + 4 combo dwordx4) for node k+1 are ISSUED before node k's
// VALU chain runs, double-buffered in registers (k-loop fully unrolled ->
// k&1 indexing is compile-time; rule #20 safe). Gather+compute are
// unconditional (clamped node); only the As write is guarded -> branch-free
// pipeline. ~16 outstanding 16B loads/wave vs 8 (compiler alone wouldn't
// hold two nodes' gather data: round-8 VGPR stayed at 56).
__launch_bounds__(256, 4)
__global__ void layer_fused(const unsigned short* __restrict__ xin,
                            const int* __restrict__ epos,
                            const unsigned* __restrict__ e_info,
                            const unsigned short* __restrict__ combo,
                            const short* __restrict__ Wt1, const short* __restrict__ Wt2,
                            const float* __restrict__ b1, const float* __restrict__ g1,
                            const float* __restrict__ be1, const float* __restrict__ m1,
                            const float* __restrict__ v1,
                            const float* __restrict__ b2, const float* __restrict__ g2,
                            const float* __restrict__ be2, const float* __restrict__ m2,
                            const float* __restrict__ v2,
                            const int* __restrict__ batch,
                            unsigned short* __restrict__ xout,
                            float* __restrict__ pool_slot) {
    __shared__ short As[32 * 136];
    __shared__ int sbg[32];
    const int tid  = threadIdx.x;
    const int lane = tid & 63;
    const int wave = tid >> 6;
    const int row0 = blockIdx.x * 32;
    const int gmin = batch[row0];

    if (tid < 32) {
        int row = row0 + tid;
        sbg[tid] = (row < NN) ? batch[row] - gmin : -1;
    }

    // ---- phase A ----
    const int eg = lane >> 4;            // slot sub-group 0..3
    const int f  = (lane & 15) * 8;      // feature offset
    const int node0 = row0 + wave * 8;

    // deg prefetch: lane j holds epos[node0 + (j&7)]
    int degp;
    {
        int nk = node0 + (lane & 7);
        if (nk >= NN) nk = NN - 1;
        degp = epos[nk];
    }
    // e_info prefetch: one dwordx4 per node (this lane's slots {4eg..4eg+3})
    uint4e ev[8];
#pragma unroll
    for (int k = 0; k < 8; ++k) {
        int nk = node0 + k;
        if (nk >= NN) nk = NN - 1;
        ev[k] = __builtin_nontemporal_load(
            (const uint4e*)&e_info[(size_t)nk * ESTRIDE + eg * 4]);
    }

    // double-buffered gather registers
    uint4 xg[2][4], cg[2][4];
#define GATHER(B, K)                                                            \
    do {                                                                        \
        xg[B][0] = *(const uint4*)&xin[(size_t)(ev[K].x & 0xFFFFu) * DD + f];   \
        cg[B][0] = *(const uint4*)&combo[(size_t)(ev[K].x >> 16) * DD + f];     \
        xg[B][1] = *(const uint4*)&xin[(size_t)(ev[K].y & 0xFFFFu) * DD + f];   \
        cg[B][1] = *(const uint4*)&combo[(size_t)(ev[K].y >> 16) * DD + f];     \
        xg[B][2] = *(const uint4*)&xin[(size_t)(ev[K].z & 0xFFFFu) * DD + f];   \
        cg[B][2] = *(const uint4*)&combo[(size_t)(ev[K].z >> 16) * DD + f];     \
        xg[B][3] = *(const uint4*)&xin[(size_t)(ev[K].w & 0xFFFFu) * DD + f];   \
        cg[B][3] = *(const uint4*)&combo[(size_t)(ev[K].w >> 16) * DD + f];     \
    } while (0)

    GATHER(0, 0);
#pragma unroll
    for (int k = 0; k < 8; ++k) {
        const int cur = k & 1;
        const int nxt = cur ^ 1;
        if (k < 7) GATHER(nxt, k + 1);   // issue next node's gathers NOW

        float acc[8];
#pragma unroll
        for (int i = 0; i < 8; ++i) acc[i] = 0.f;
        acc8(acc, xg[cur][0], cg[cur][0]);
        acc8(acc, xg[cur][1], cg[cur][1]);
        acc8(acc, xg[cur][2], cg[cur][2]);
        acc8(acc, xg[cur][3], cg[cur][3]);

        const int nl = wave * 8 + k;
        const int node = row0 + nl;
        int deg = __shfl(degp, k, 64);
        if (deg > 16 && node < NN) {     // ~10% of nodes; slow path
            if (deg > ESTRIDE) deg = ESTRIDE;
            const int base = node * ESTRIDE;
            const int pe = base + ((deg + 7) & ~7);
            for (int p = base + 16; p < pe; p += 8) {
                // 8 slots; this lane takes {p+2eg, p+2eg+1}
                uint2 jv = *(const uint2*)&e_info[p + eg * 2];
                uint4 ax0 = *(const uint4*)&xin[(size_t)(jv.x & 0xFFFFu) * DD + f];
                uint4 ac0 = *(const uint4*)&combo[(size_t)(jv.x >> 16) * DD + f];
                uint4 ax1 = *(const uint4*)&xin[(size_t)(jv.y & 0xFFFFu) * DD + f];
                uint4 ac1 = *(const uint4*)&combo[(size_t)(jv.y >> 16) * DD + f];
                acc8(acc, ax0, ac0);
                acc8(acc, ax1, ac1);
            }
        }

        // reduce across the 4 slot sub-groups (lanes differing in bits 4,5)
#pragma unroll
        for (int i = 0; i < 8; ++i) {
            acc[i] += __shfl_xor(acc[i], 16, 64);
            acc[i] += __shfl_xor(acc[i], 32, 64);
        }
        if (lane < 16) {
            if (node < NN) {
                uint4 self = *(const uint4*)&xin[(size_t)node * DD + f];
                uint4 o;
                o.x = pk2(acc[0] + blo(self.x), acc[1] + bhi(self.x));
                o.y = pk2(acc[2] + blo(self.y), acc[3] + bhi(self.y));
                o.z = pk2(acc[4] + blo(self.z), acc[5] + bhi(self.z));
                o.w = pk2(acc[6] + blo(self.w), acc[7] + bhi(self.w));
                *(uint4*)&As[nl * 136 + f] = o;
            } else {
                *(uint4*)&As[nl * 136 + f] = make_uint4(0, 0, 0, 0);
            }
        }
    }
#undef GATHER
    __syncthreads();

    // ---- phase B: conv + BN + pooling (reads As) ----
    const int col   = wave * 32 + (lane & 31);
    const int khalf = (lane >> 5) * 8;
    const int arow  = lane & 31;
    const int rbase = 4 * (lane >> 5);

    short8 bf[8];
#pragma unroll
    for (int ch = 0; ch < 8; ++ch)
        bf[ch] = *(const short8*)&Wt1[col * DD + ch * 16 + khalf];

    const float sc1 = g1[col] * rsqrtf(v1[col] + BN_EPS);
    const float sh1 = fmaf(b1[col] - m1[col], sc1, be1[col]);
    const float sc2 = g2[col] * rsqrtf(v2[col] + BN_EPS);
    const float sh2 = fmaf(b2[col] - m2[col], sc2, be2[col]);

    float16 acc0 = {0.f,0.f,0.f,0.f,0.f,0.f,0.f,0.f,0.f,0.f,0.f,0.f,0.f,0.f,0.f,0.f};
#pragma unroll
    for (int ch = 0; ch < 8; ++ch) {
        short8 a0 = *(const short8*)&As[arow * 136 + ch * 16 + khalf];
        acc0 = __builtin_amdgcn_mfma_f32_32x32x16_bf16(a0, bf[ch], acc0, 0, 0, 0);
    }

#pragma unroll
    for (int ch = 0; ch < 8; ++ch)
        bf[ch] = *(const short8*)&Wt2[col * DD + ch * 16 + khalf];

    __syncthreads();
#pragma unroll
    for (int r = 0; r < 16; ++r) {
        int rl = (r & 3) + 8 * (r >> 2) + rbase;
        As[rl * 136 + col] = (short)f2b(fmaxf(fmaf(acc0[r], sc1, sh1), 0.f));
    }
    __syncthreads();

    acc0 = float16{0.f,0.f,0.f,0.f,0.f,0.f,0.f,0.f,0.f,0.f,0.f,0.f,0.f,0.f,0.f,0.f};
#pragma unroll
    for (int ch = 0; ch < 8; ++ch) {
        short8 a0 = *(const short8*)&As[arow * 136 + ch * 16 + khalf];
        acc0 = __builtin_amdgcn_mfma_f32_32x32x16_bf16(a0, bf[ch], acc0, 0, 0, 0);
    }

    float pg0 = 0.f, pg1 = 0.f, pg2 = 0.f, pg3 = 0.f;
#pragma unroll
    for (int r = 0; r < 16; ++r) {
        int rl  = (r & 3) + 8 * (r >> 2) + rbase;
        int row = row0 + rl;
        float v0 = fmaxf(fmaf(acc0[r], sc2, sh2), 0.f);
        if (row < NN) xout[(size_t)row * DD + col] = f2b(v0);
        int ga = sbg[rl];
        pg0 += (ga == 0) ? v0 : 0.f;
        pg1 += (ga == 1) ? v0 : 0.f;
        pg2 += (ga == 2) ? v0 : 0.f;
        pg3 += (ga == 3) ? v0 : 0.f;
    }
    pg0 += __shfl_down(pg0, 32);
    pg1 += __shfl_down(pg1, 32);
    pg2 += __shfl_down(pg2, 32);
    pg3 += __shfl_down(pg3, 32);
    if (lane < 32) {
        if (pg0 != 0.f)                  atomicAdd(&pool_slot[(gmin    ) * DD + col], pg0);
        if (pg1 != 0.f && gmin + 1 < GG) atomicAdd(&pool_slot[(gmin + 1) * DD + col], pg1);
        if (pg2 != 0.f && gmin + 2 < GG) atomicAdd(&pool_slot[(gmin + 2) * DD + col], pg2);
        if (pg3 != 0.f && gmin + 3 < GG) atomicAdd(&pool_slot[(gmin + 3) * DD + col], pg3);
    }
}

// ====== final head: out[g,:] = inv[g]*sum_l pooled_l@fcw_l + sum_l fcb_l ======
__launch_bounds__(64)
__global__ void head(const int* __restrict__ batch, const float* __restrict__ pooled,
                     const float* __restrict__ fcw, const float* __restrict__ fcb,
                     float* __restrict__ out) {
    int g = blockIdx.x, t = threadIdx.x;
    __shared__ float part[LL + 1][OO];
    // wave-uniform binary searches on sorted batch -> graph size
    int r0, r1;
    {
        int lo = 0, hi = NN;
        while (lo < hi) { int m = (lo + hi) >> 1; if (batch[m] < g) lo = m + 1; else hi = m; }
        r0 = lo;
        lo = 0; hi = NN;
        while (lo < hi) { int m = (lo + hi) >> 1; if (batch[m] < g + 1) lo = m + 1; else hi = m; }
        r1 = lo;
    }
    const float invg = 1.0f / fmaxf((float)(r1 - r0), 1.0f);
    if (t < (LL + 1) * OO) {
        int l = t / OO, o2 = t - l * OO;
        const float* p = pooled + ((size_t)l * GG + g) * DD;
        const float* w = fcw + (size_t)l * DD * OO + o2;
        float s = 0.f;
        for (int d2 = 0; d2 < DD; ++d2) s = fmaf(p[d2], w[(size_t)d2 * OO], s);
        part[l][o2] = s;
    }
    __syncthreads();
    if (t < OO) {
        float sp = 0.f, sb2 = 0.f;
#pragma unroll
        for (int l = 0; l < LL + 1; ++l) { sp += part[l][t]; sb2 += fcb[l * OO + t]; }
        out[g * OO + t] = sp * invg + sb2;
    }
}

extern "C" void kernel_launch(void* const* d_in, const int* in_sizes, int n_in,
                              void* d_out, int out_size, void* d_ws, size_t ws_size,
                              hipStream_t stream) {
    const float* x_in    = (const float*)d_in[0];
    const int*   ei      = (const int*)d_in[1];
    const int*   eattr   = (const int*)d_in[2];
    const int*   batch   = (const int*)d_in[3];
    const float* bond    = (const float*)d_in[4];
    const float* conv_w1 = (const float*)d_in[5];
    const float* conv_b1 = (const float*)d_in[6];
    const float* cbg     = (const float*)d_in[7];
    const float* cbb     = (const float*)d_in[8];
    const float* cbm     = (const float*)d_in[9];
    const float* cbv     = (const float*)d_in[10];
    const float* conv_w2 = (const float*)d_in[11];
    const float* conv_b2 = (const float*)d_in[12];
    const float* bg      = (const float*)d_in[13];
    const float* bb      = (const float*)d_in[14];
    const float* bm      = (const float*)d_in[15];
    const float* bv      = (const float*)d_in[16];
    const float* fcw     = (const float*)d_in[17];
    const float* fcb     = (const float*)d_in[18];
    float* out = (float*)d_out;

    // ---- workspace carve-up (16B-aligned chunks) ----
    char* base = (char*)d_ws;
    size_t o = 0;
    auto carve = [&](size_t bytes) { void* p = base + o; o += (bytes + 15) & ~(size_t)15; return p; };
    unsigned short* xbA    = (unsigned short*)carve((size_t)NN * DD * 2);
    unsigned short* xbB    = (unsigned short*)carve((size_t)NN * DD * 2);
    unsigned short* combo  = (unsigned short*)carve((size_t)LL * CPAD * DD * 2);
    short*          wt     = (short*)carve((size_t)10 * DD * DD * 2);
    // contiguous zero-region: epos | pooled[6][G][D] (slot 0 = pool0)
    const size_t ZBYTES = (size_t)NN * 4 + (size_t)(LL + 1) * GG * DD * 4;
    int*            epos   = (int*)carve(ZBYTES);
    float*          pooled = (float*)((char*)epos + (size_t)NN * 4);
    unsigned*       e_info = (unsigned*)carve((size_t)NN * ESTRIDE * 4);

    (void)hipMemsetAsync(epos, 0, ZBYTES, stream);
    (void)hipMemsetAsync(e_info, 0x02, (size_t)NN * ESTRIDE * 4, stream);  // sentinel fill

    prep<<<B_PREP, 256, 0, stream>>>(x_in, ei, eattr, batch, bond, conv_w1, conv_w2,
                                     (unsigned*)xbA, combo, wt, epos, e_info, pooled);

    const int layer_blocks = (NN + 31) / 32;    // 1563
    unsigned short* xcur = xbA;   // layer input (complete previous activation)
    unsigned short* xnxt = xbB;   // layer output (ping-pong; in-place would race)
    for (int i = 0; i < LL; ++i) {
        layer_fused<<<layer_blocks, 256, 0, stream>>>(
            xcur, epos, e_info, combo + (size_t)i * CPAD * DD,
            wt + (size_t)i * DD * DD, wt + (size_t)(5 + i) * DD * DD,
            conv_b1 + (size_t)i * DD, cbg + (size_t)i * DD, cbb + (size_t)i * DD,
            cbm + (size_t)i * DD, cbv + (size_t)i * DD,
            conv_b2 + (size_t)i * DD, bg + (size_t)i * DD, bb + (size_t)i * DD,
            bm + (size_t)i * DD, bv + (size_t)i * DD,
            batch, xnxt, pooled + (size_t)(i + 1) * GG * DD);
        unsigned short* tmp = xcur; xcur = xnxt; xnxt = tmp;
    }
    head<<<GG, 64, 0, stream>>>(batch, pooled, fcw, fcb, out);
}

// Round 10
// 383.656 us; speedup vs baseline: 1.1203x; 1.0269x over previous
//
#include <hip/hip_runtime.h>

#define NN 50000
#define EE 600000
#define DD 128
#define GG 256
#define LL 5
#define OO 10
#define BN_EPS 1e-5f
#define CPAD 515      // 512 combos + 3 sentinel (-1e30) rows (slot 0x02020202 -> cidx 514)
#define ESTRIDE 40    // fixed CSR slots per node (P(deg>40)~1e-9 at lambda=12)

// prep kernel block-range sizes (virtual ids; physical blocks are striped through
// all sections via a bijective mod-permutation so latency-bound atomic work
// overlaps BW-bound streaming work instead of running as serial phases)
#define B_SCAT  2344                       // ceil(EE/256)
#define B_COMBO 1288                       // ceil(LL*CPAD*DD / 256)
#define B_WT    160                        // 10 mats x 16 (32x32) tiles
#define B_CVT   3125                       // NN*DD/8 / 256 (pure convert)
#define B_POOL  2048                       // 8 blocks per graph
#define B_PREP  (B_SCAT + B_COMBO + B_WT + B_CVT + B_POOL)  // 8965 = 5*11*163, coprime w/ 1021

typedef __attribute__((ext_vector_type(8))) short short8;
typedef __attribute__((ext_vector_type(16))) float float16;
typedef __attribute__((ext_vector_type(4))) unsigned uint4e;   // nontemporal-compatible

__device__ __forceinline__ unsigned short f2b(float f) {   // fp32 -> bf16 RNE
    unsigned u = __float_as_uint(f);
    unsigned r = u + 0x7FFFu + ((u >> 16) & 1u);
    return (unsigned short)(r >> 16);
}
__device__ __forceinline__ unsigned pk2(float lo, float hi) {
    return (unsigned)f2b(lo) | ((unsigned)f2b(hi) << 16);
}
__device__ __forceinline__ float blo(unsigned u) { return __uint_as_float(u << 16); }
__device__ __forceinline__ float bhi(unsigned u) { return __uint_as_float(u & 0xFFFF0000u); }

__device__ __forceinline__ void acc8(float* acc, uint4 xv, uint4 cv) {
    acc[0] += fmaxf(blo(xv.x) + blo(cv.x), 0.f);
    acc[1] += fmaxf(bhi(xv.x) + bhi(cv.x), 0.f);
    acc[2] += fmaxf(blo(xv.y) + blo(cv.y), 0.f);
    acc[3] += fmaxf(bhi(xv.y) + bhi(cv.y), 0.f);
    acc[4] += fmaxf(blo(xv.z) + blo(cv.z), 0.f);
    acc[5] += fmaxf(bhi(xv.z) + bhi(cv.z), 0.f);
    acc[6] += fmaxf(blo(xv.w) + blo(cv.w), 0.f);
    acc[7] += fmaxf(bhi(xv.w) + bhi(cv.w), 0.f);
}

// == mega prep: edge-scatter | combo | Wt-transpose | cvt_x | pool0 (striped) ==
__launch_bounds__(256)
__global__ void prep(const float* __restrict__ x, const int* __restrict__ ei,
                     const int* __restrict__ eattr, const int* __restrict__ batch,
                     const float* __restrict__ bond,
                     const float* __restrict__ w1, const float* __restrict__ w2,
                     unsigned* __restrict__ xb4, unsigned short* __restrict__ combo,
                     short* __restrict__ wt, int* __restrict__ epos,
                     unsigned* __restrict__ e_info, float* __restrict__ pooled0) {
    // bijective stripe: gcd(1021, 8965)=1 -> all sections co-resident
    const int bid = (int)(((long long)blockIdx.x * 1021) % B_PREP);
    const int t = threadIdx.x;
    if (bid < B_SCAT) {
        // scatter edges into fixed-stride CSR. Deps: epos==0, e_info==0x02020202
        // (both memset before launch). Unfilled slots stay = sentinel.
        int e = bid * 256 + t;
        if (e < EE) {
            int dst = ei[EE + e];
            int slot = atomicAdd(&epos[dst], 1);
            if (slot < ESTRIDE) {
                unsigned cidx = (unsigned)eattr[e * 3 + 0] | ((unsigned)eattr[e * 3 + 1] << 3)
                              | ((unsigned)eattr[e * 3 + 2] << 6);
                e_info[dst * ESTRIDE + slot] = (unsigned)ei[e] | (cidx << 16);
            }
        }
    } else if (bid < B_SCAT + B_COMBO) {
        int e = (bid - B_SCAT) * 256 + t;
        if (e < LL * CPAD * DD) {
            int l = e / (CPAD * DD), rem = e - l * (CPAD * DD);
            int c = rem / DD, d = rem - c * DD;
            float s;
            if (c >= 512) s = -1e30f;                     // sentinel rows: relu(x+s)==0
            else {
                const float* b_ = bond + (size_t)l * 3 * 8 * DD;
                s = b_[(c & 7) * DD + d] + b_[(8 + ((c >> 3) & 7)) * DD + d]
                  + b_[(16 + (c >> 6)) * DD + d];
            }
            combo[e] = f2b(s);
        }
    } else if (bid < B_SCAT + B_COMBO + B_WT) {
        // coalesced transpose: wt[mat][c][k] = bf16(W[mat][k][c]), 32x32 LDS tiles
        __shared__ float tile[32][33];
        int b = bid - B_SCAT - B_COMBO;
        int mat = b >> 4, tl = b & 15;
        int k0 = (tl >> 2) * 32, c0 = (tl & 3) * 32;
        const float* W = (mat < 5) ? (w1 + (size_t)mat * DD * DD)
                                   : (w2 + (size_t)(mat - 5) * DD * DD);
        int j = t & 31, q = t >> 5;
#pragma unroll
        for (int rr = 0; rr < 4; ++rr) {
            int row = q + rr * 8;
            tile[row][j] = W[(size_t)(k0 + row) * DD + c0 + j];
        }
        __syncthreads();
#pragma unroll
        for (int rr = 0; rr < 4; ++rr) {
            int cr = q + rr * 8;
            wt[(size_t)mat * DD * DD + (size_t)(c0 + cr) * DD + k0 + j] = (short)f2b(tile[j][cr]);
        }
    } else if (bid < B_SCAT + B_COMBO + B_WT + B_CVT) {
        // pure stream: x (fp32) -> xb (bf16), 8 elems/thread
        int gid = (bid - (B_SCAT + B_COMBO + B_WT)) * 256 + t;
        const float4* xp = (const float4*)(x + (size_t)gid * 8);
        float4 a = xp[0], c4 = xp[1];
        uint4 o;
        o.x = pk2(a.x, a.y); o.y = pk2(a.z, a.w);
        o.z = pk2(c4.x, c4.y); o.w = pk2(c4.z, c4.w);
        ((uint4*)xb4)[gid] = o;
    } else {
        // pool0: per-graph contiguous row-sum of fp32 x. 8 blocks/graph; rows
        // found by wave-uniform binary search on sorted batch; one LDS-reduced
        // atomicAdd per column per block (262K atomics total, overlapped by stripe).
        __shared__ float sm[DD];
        int b = bid - (B_SCAT + B_COMBO + B_WT + B_CVT);
        int g = b >> 3, s = b & 7;
        int r0, r1;
        {
            int lo = 0, hi = NN;
            while (lo < hi) { int m = (lo + hi) >> 1; if (batch[m] < g) lo = m + 1; else hi = m; }
            r0 = lo;
            lo = 0; hi = NN;
            while (lo < hi) { int m = (lo + hi) >> 1; if (batch[m] < g + 1) lo = m + 1; else hi = m; }
            r1 = lo;
        }
        int col = t & 127, par = t >> 7;
        float ssum = 0.f;
        for (int r = r0 + s * 2 + par; r < r1; r += 16) ssum += x[(size_t)r * DD + col];
        if (par == 0) sm[col] = ssum;
        __syncthreads();
        if (par == 1) {
            float v = sm[col] + ssum;
            if (v != 0.f) atomicAdd(&pooled0[(size_t)g * DD + col], v);
        }
    }
}

// ====== fused layer: CSR aggregation (phase A) + conv/BN/pool (phase B) ======
// Phase A: manual 2-deep software pipeline, PINNED with sched_barrier(0).
// Round-9 lesson: without the fence the compiler sinks next-node gathers to
// just before use (VGPR stayed 64 -> buffers never coexist). The fence (a
// compile-time scheduling barrier, no emitted instruction) keeps node k+1's
// 9 loads (4 xin + 4 combo + self) issued BEFORE node k's VALU chain ->
// ~18 outstanding loads/wave. launch_bounds 4->3 waves/EU: live set needs
// ~130-150 VGPR; a 128 cap would spill (rule #20).
__launch_bounds__(256, 3)
__global__ void layer_fused(const unsigned short* __restrict__ xin,
                            const int* __restrict__ epos,
                            const unsigned* __restrict__ e_info,
                            const unsigned short* __restrict__ combo,
                            const short* __restrict__ Wt1, const short* __restrict__ Wt2,
                            const float* __restrict__ b1, const float* __restrict__ g1,
                            const float* __restrict__ be1, const float* __restrict__ m1,
                            const float* __restrict__ v1,
                            const float* __restrict__ b2, const float* __restrict__ g2,
                            const float* __restrict__ be2, const float* __restrict__ m2,
                            const float* __restrict__ v2,
                            const int* __restrict__ batch,
                            unsigned short* __restrict__ xout,
                            float* __restrict__ pool_slot) {
    __shared__ short As[32 * 136];
    __shared__ int sbg[32];
    const int tid  = threadIdx.x;
    const int lane = tid & 63;
    const int wave = tid >> 6;
    const int row0 = blockIdx.x * 32;
    const int gmin = batch[row0];

    if (tid < 32) {
        int row = row0 + tid;
        sbg[tid] = (row < NN) ? batch[row] - gmin : -1;
    }

    // ---- phase A ----
    const int eg = lane >> 4;            // slot sub-group 0..3
    const int f  = (lane & 15) * 8;      // feature offset
    const int node0 = row0 + wave * 8;

    // deg prefetch: lane j holds epos[node0 + (j&7)]
    int degp;
    {
        int nk = node0 + (lane & 7);
        if (nk >= NN) nk = NN - 1;
        degp = epos[nk];
    }
    // e_info prefetch: one dwordx4 per node (this lane's slots {4eg..4eg+3})
    uint4e ev[8];
#pragma unroll
    for (int k = 0; k < 8; ++k) {
        int nk = node0 + k;
        if (nk >= NN) nk = NN - 1;
        ev[k] = __builtin_nontemporal_load(
            (const uint4e*)&e_info[(size_t)nk * ESTRIDE + eg * 4]);
    }

    // double-buffered gather registers (+ prefetched self row for the residual)
    uint4 xg[2][4], cg[2][4], sf[2];
#define GATHER(B, K)                                                            \
    do {                                                                        \
        xg[B][0] = *(const uint4*)&xin[(size_t)(ev[K].x & 0xFFFFu) * DD + f];   \
        cg[B][0] = *(const uint4*)&combo[(size_t)(ev[K].x >> 16) * DD + f];     \
        xg[B][1] = *(const uint4*)&xin[(size_t)(ev[K].y & 0xFFFFu) * DD + f];   \
        cg[B][1] = *(const uint4*)&combo[(size_t)(ev[K].y >> 16) * DD + f];     \
        xg[B][2] = *(const uint4*)&xin[(size_t)(ev[K].z & 0xFFFFu) * DD + f];   \
        cg[B][2] = *(const uint4*)&combo[(size_t)(ev[K].z >> 16) * DD + f];     \
        xg[B][3] = *(const uint4*)&xin[(size_t)(ev[K].w & 0xFFFFu) * DD + f];   \
        cg[B][3] = *(const uint4*)&combo[(size_t)(ev[K].w >> 16) * DD + f];     \
        int nkk = node0 + (K); if (nkk >= NN) nkk = NN - 1;                     \
        sf[B] = *(const uint4*)&xin[(size_t)nkk * DD + f];                      \
    } while (0)

    GATHER(0, 0);
    __builtin_amdgcn_sched_barrier(0);   // pin buffer-0 loads before the loop
#pragma unroll
    for (int k = 0; k < 8; ++k) {
        const int cur = k & 1;
        const int nxt = cur ^ 1;
        if (k < 7) {
            GATHER(nxt, k + 1);          // issue next node's gathers NOW
            __builtin_amdgcn_sched_barrier(0);  // forbid sinking them below
        }

        float acc[8];
#pragma unroll
        for (int i = 0; i < 8; ++i) acc[i] = 0.f;
        acc8(acc, xg[cur][0], cg[cur][0]);
        acc8(acc, xg[cur][1], cg[cur][1]);
        acc8(acc, xg[cur][2], cg[cur][2]);
        acc8(acc, xg[cur][3], cg[cur][3]);

        const int nl = wave * 8 + k;
        const int node = row0 + nl;
        int deg = __shfl(degp, k, 64);
        if (deg > 16 && node < NN) {     // ~10% of nodes; slow path
            if (deg > ESTRIDE) deg = ESTRIDE;
            const int base = node * ESTRIDE;
            const int pe = base + ((deg + 7) & ~7);
            for (int p = base + 16; p < pe; p += 8) {
                // 8 slots; this lane takes {p+2eg, p+2eg+1}
                uint2 jv = *(const uint2*)&e_info[p + eg * 2];
                uint4 ax0 = *(const uint4*)&xin[(size_t)(jv.x & 0xFFFFu) * DD + f];
                uint4 ac0 = *(const uint4*)&combo[(size_t)(jv.x >> 16) * DD + f];
                uint4 ax1 = *(const uint4*)&xin[(size_t)(jv.y & 0xFFFFu) * DD + f];
                uint4 ac1 = *(const uint4*)&combo[(size_t)(jv.y >> 16) * DD + f];
                acc8(acc, ax0, ac0);
                acc8(acc, ax1, ac1);
            }
        }

        // reduce across the 4 slot sub-groups (lanes differing in bits 4,5)
#pragma unroll
        for (int i = 0; i < 8; ++i) {
            acc[i] += __shfl_xor(acc[i], 16, 64);
            acc[i] += __shfl_xor(acc[i], 32, 64);
        }
        if (lane < 16) {
            if (node < NN) {
                uint4 self = sf[cur];
                uint4 o;
                o.x = pk2(acc[0] + blo(self.x), acc[1] + bhi(self.x));
                o.y = pk2(acc[2] + blo(self.y), acc[3] + bhi(self.y));
                o.z = pk2(acc[4] + blo(self.z), acc[5] + bhi(self.z));
                o.w = pk2(acc[6] + blo(self.w), acc[7] + bhi(self.w));
                *(uint4*)&As[nl * 136 + f] = o;
            } else {
                *(uint4*)&As[nl * 136 + f] = make_uint4(0, 0, 0, 0);
            }
        }
    }
#undef GATHER
    __syncthreads();

    // ---- phase B: conv + BN + pooling (reads As) ----
    const int col   = wave * 32 + (lane & 31);
    const int khalf = (lane >> 5) * 8;
    const int arow  = lane & 31;
    const int rbase = 4 * (lane >> 5);

    short8 bf[8];
#pragma unroll
    for (int ch = 0; ch < 8; ++ch)
        bf[ch] = *(const short8*)&Wt1[col * DD + ch * 16 + khalf];

    const float sc1 = g1[col] * rsqrtf(v1[col] + BN_EPS);
    const float sh1 = fmaf(b1[col] - m1[col], sc1, be1[col]);
    const float sc2 = g2[col] * rsqrtf(v2[col] + BN_EPS);
    const float sh2 = fmaf(b2[col] - m2[col], sc2, be2[col]);

    float16 acc0 = {0.f,0.f,0.f,0.f,0.f,0.f,0.f,0.f,0.f,0.f,0.f,0.f,0.f,0.f,0.f,0.f};
#pragma unroll
    for (int ch = 0; ch < 8; ++ch) {
        short8 a0 = *(const short8*)&As[arow * 136 + ch * 16 + khalf];
        acc0 = __builtin_amdgcn_mfma_f32_32x32x16_bf16(a0, bf[ch], acc0, 0, 0, 0);
    }

#pragma unroll
    for (int ch = 0; ch < 8; ++ch)
        bf[ch] = *(const short8*)&Wt2[col * DD + ch * 16 + khalf];

    __syncthreads();
#pragma unroll
    for (int r = 0; r < 16; ++r) {
        int rl = (r & 3) + 8 * (r >> 2) + rbase;
        As[rl * 136 + col] = (short)f2b(fmaxf(fmaf(acc0[r], sc1, sh1), 0.f));
    }
    __syncthreads();

    acc0 = float16{0.f,0.f,0.f,0.f,0.f,0.f,0.f,0.f,0.f,0.f,0.f,0.f,0.f,0.f,0.f,0.f};
#pragma unroll
    for (int ch = 0; ch < 8; ++ch) {
        short8 a0 = *(const short8*)&As[arow * 136 + ch * 16 + khalf];
        acc0 = __builtin_amdgcn_mfma_f32_32x32x16_bf16(a0, bf[ch], acc0, 0, 0, 0);
    }

    float pg0 = 0.f, pg1 = 0.f, pg2 = 0.f, pg3 = 0.f;
#pragma unroll
    for (int r = 0; r < 16; ++r) {
        int rl  = (r & 3) + 8 * (r >> 2) + rbase;
        int row = row0 + rl;
        float v0 = fmaxf(fmaf(acc0[r], sc2, sh2), 0.f);
        if (row < NN) xout[(size_t)row * DD + col] = f2b(v0);
        int ga = sbg[rl];
        pg0 += (ga == 0) ? v0 : 0.f;
        pg1 += (ga == 1) ? v0 : 0.f;
        pg2 += (ga == 2) ? v0 : 0.f;
        pg3 += (ga == 3) ? v0 : 0.f;
    }
    pg0 += __shfl_down(pg0, 32);
    pg1 += __shfl_down(pg1, 32);
    pg2 += __shfl_down(pg2, 32);
    pg3 += __shfl_down(pg3, 32);
    if (lane < 32) {
        if (pg0 != 0.f)                  atomicAdd(&pool_slot[(gmin    ) * DD + col], pg0);
        if (pg1 != 0.f && gmin + 1 < GG) atomicAdd(&pool_slot[(gmin + 1) * DD + col], pg1);
        if (pg2 != 0.f && gmin + 2 < GG) atomicAdd(&pool_slot[(gmin + 2) * DD + col], pg2);
        if (pg3 != 0.f && gmin + 3 < GG) atomicAdd(&pool_slot[(gmin + 3) * DD + col], pg3);
    }
}

// ====== final head: out[g,:] = inv[g]*sum_l pooled_l@fcw_l + sum_l fcb_l ======
__launch_bounds__(64)
__global__ void head(const int* __restrict__ batch, const float* __restrict__ pooled,
                     const float* __restrict__ fcw, const float* __restrict__ fcb,
                     float* __restrict__ out) {
    int g = blockIdx.x, t = threadIdx.x;
    __shared__ float part[LL + 1][OO];
    // wave-uniform binary searches on sorted batch -> graph size
    int r0, r1;
    {
        int lo = 0, hi = NN;
        while (lo < hi) { int m = (lo + hi) >> 1; if (batch[m] < g) lo = m + 1; else hi = m; }
        r0 = lo;
        lo = 0; hi = NN;
        while (lo < hi) { int m = (lo + hi) >> 1; if (batch[m] < g + 1) lo = m + 1; else hi = m; }
        r1 = lo;
    }
    const float invg = 1.0f / fmaxf((float)(r1 - r0), 1.0f);
    if (t < (LL + 1) * OO) {
        int l = t / OO, o2 = t - l * OO;
        const float* p = pooled + ((size_t)l * GG + g) * DD;
        const float* w = fcw + (size_t)l * DD * OO + o2;
        float s = 0.f;
        for (int d2 = 0; d2 < DD; ++d2) s = fmaf(p[d2], w[(size_t)d2 * OO], s);
        part[l][o2] = s;
    }
    __syncthreads();
    if (t < OO) {
        float sp = 0.f, sb2 = 0.f;
#pragma unroll
        for (int l = 0; l < LL + 1; ++l) { sp += part[l][t]; sb2 += fcb[l * OO + t]; }
        out[g * OO + t] = sp * invg + sb2;
    }
}

extern "C" void kernel_launch(void* const* d_in, const int* in_sizes, int n_in,
                              void* d_out, int out_size, void* d_ws, size_t ws_size,
                              hipStream_t stream) {
    const float* x_in    = (const float*)d_in[0];
    const int*   ei      = (const int*)d_in[1];
    const int*   eattr   = (const int*)d_in[2];
    const int*   batch   = (const int*)d_in[3];
    const float* bond    = (const float*)d_in[4];
    const float* conv_w1 = (const float*)d_in[5];
    const float* conv_b1 = (const float*)d_in[6];
    const float* cbg     = (const float*)d_in[7];
    const float* cbb     = (const float*)d_in[8];
    const float* cbm     = (const float*)d_in[9];
    const float* cbv     = (const float*)d_in[10];
    const float* conv_w2 = (const float*)d_in[11];
    const float* conv_b2 = (const float*)d_in[12];
    const float* bg      = (const float*)d_in[13];
    const float* bb      = (const float*)d_in[14];
    const float* bm      = (const float*)d_in[15];
    const float* bv      = (const float*)d_in[16];
    const float* fcw     = (const float*)d_in[17];
    const float* fcb     = (const float*)d_in[18];
    float* out = (float*)d_out;

    // ---- workspace carve-up (16B-aligned chunks) ----
    char* base = (char*)d_ws;
    size_t o = 0;
    auto carve = [&](size_t bytes) { void* p = base + o; o += (bytes + 15) & ~(size_t)15; return p; };
    unsigned short* xbA    = (unsigned short*)carve((size_t)NN * DD * 2);
    unsigned short* xbB    = (unsigned short*)carve((size_t)NN * DD * 2);
    unsigned short* combo  = (unsigned short*)carve((size_t)LL * CPAD * DD * 2);
    short*          wt     = (short*)carve((size_t)10 * DD * DD * 2);
    // contiguous zero-region: epos | pooled[6][G][D] (slot 0 = pool0)
    const size_t ZBYTES = (size_t)NN * 4 + (size_t)(LL + 1) * GG * DD * 4;
    int*            epos   = (int*)carve(ZBYTES);
    float*          pooled = (float*)((char*)epos + (size_t)NN * 4);
    unsigned*       e_info = (unsigned*)carve((size_t)NN * ESTRIDE * 4);

    (void)hipMemsetAsync(epos, 0, ZBYTES, stream);
    (void)hipMemsetAsync(e_info, 0x02, (size_t)NN * ESTRIDE * 4, stream);  // sentinel fill

    prep<<<B_PREP, 256, 0, stream>>>(x_in, ei, eattr, batch, bond, conv_w1, conv_w2,
                                     (unsigned*)xbA, combo, wt, epos, e_info, pooled);

    const int layer_blocks = (NN + 31) / 32;    // 1563
    unsigned short* xcur = xbA;   // layer input (complete previous activation)
    unsigned short* xnxt = xbB;   // layer output (ping-pong; in-place would race)
    for (int i = 0; i < LL; ++i) {
        layer_fused<<<layer_blocks, 256, 0, stream>>>(
            xcur, epos, e_info, combo + (size_t)i * CPAD * DD,
            wt + (size_t)i * DD * DD, wt + (size_t)(5 + i) * DD * DD,
            conv_b1 + (size_t)i * DD, cbg + (size_t)i * DD, cbb + (size_t)i * DD,
            cbm + (size_t)i * DD, cbv + (size_t)i * DD,
            conv_b2 + (size_t)i * DD, bg + (size_t)i * DD, bb + (size_t)i * DD,
            bm + (size_t)i * DD, bv + (size_t)i * DD,
            batch, xnxt, pooled + (size_t)(i + 1) * GG * DD);
        unsigned short* tmp = xcur; xcur = xnxt; xnxt = tmp;
    }
    head<<<GG, 64, 0, stream>>>(batch, pooled, fcw, fcb, out);
}